// Round 8
// baseline (2394.889 us; speedup 1.0000x reference)
//
#include <hip/hip_runtime.h>
#include <hip/hip_bf16.h>
#include <math.h>

// Tree-LSTM "LogicEncoder": D=10, N=1023 nodes, B=128, LD=256, K=2.
// Round 8: SINGLE CHANGE vs round 7 — eliminate address-exposed staging arrays
// in mfma_level. aS[16]+wS[3][2] (=40 dwords) were scratch-allocated (their
// addresses are taken by *(float4*)& casts inside reference-capturing lambdas,
// defeating SROA): 40 dw x 24 iters x 524288 threads = 2.01 GB == the measured
// invariant WRITE_SIZE. Replaced with named float4/int4 registers + scalar
// pack2(). Everything else byte-identical to round 7.

#define NNODES 1023
#define BATCH  128
#define LDIM   256

typedef __attribute__((ext_vector_type(8))) short short8;
typedef __attribute__((ext_vector_type(4))) float f32x4;

__device__ __forceinline__ float sigmoidf_(float x) {
    return 1.f / (1.f + expf(-x));
}

// fp32 -> 3x bf16, round-to-nearest-even at each stage; residuals exact.
__device__ __forceinline__ void split3(float x, ushort& h, ushort& m, ushort& l) {
    unsigned u = __float_as_uint(x);
    unsigned hu = (u + 0x7FFFu + ((u >> 16) & 1u)) & 0xFFFF0000u;
    h = (ushort)(hu >> 16);
    float r = x - __uint_as_float(hu);
    unsigned ur = __float_as_uint(r);
    unsigned mu = (ur + 0x7FFFu + ((ur >> 16) & 1u)) & 0xFFFF0000u;
    m = (ushort)(mu >> 16);
    float r2 = r - __uint_as_float(mu);
    unsigned u2 = __float_as_uint(r2);
    l = (ushort)((u2 + 0x7FFFu + ((u2 >> 16) & 1u)) >> 16);
}

// split a pair of fp32 into packed 2xbf16 words for the 3 planes (all scalars).
__device__ __forceinline__ void pack2(float x0, float x1,
                                      unsigned& ph, unsigned& pm, unsigned& pl) {
    ushort h0, m0, l0, h1, m1, l1;
    split3(x0, h0, m0, l0);
    split3(x1, h1, m1, l1);
    ph = (unsigned)h0 | ((unsigned)h1 << 16);
    pm = (unsigned)m0 | ((unsigned)m1 << 16);
    pl = (unsigned)l0 | ((unsigned)l1 << 16);
}

// ---------------------------------------------------------------------------
// Pack Wbig (768x1024) + bias_big(1024) + Wleaf(256x512) + bias_leaf(512).
__global__ __launch_bounds__(256) void build_weights(
    const float* __restrict__ Wix, const float* __restrict__ bix,
    const float* __restrict__ Wfx, const float* __restrict__ bfx,
    const float* __restrict__ Wux, const float* __restrict__ bux,
    const float* __restrict__ Wi,  const float* __restrict__ bi,
    const float* __restrict__ Wf,  const float* __restrict__ bf,
    const float* __restrict__ Wu,  const float* __restrict__ bu,
    const float* __restrict__ Wcx, const float* __restrict__ bcx,
    const float* __restrict__ Wox, const float* __restrict__ box,
    float* __restrict__ Wbig, float* __restrict__ bias_big,
    float* __restrict__ Wleaf, float* __restrict__ bias_leaf)
{
    int i = blockIdx.x * blockDim.x + threadIdx.x;
    if (i < 768 * 1024) {
        int k = i >> 10, n = i & 1023;
        int g = n >> 8, nn = n & 255;
        float v;
        if (g == 0) {
            v = (k < 256) ? Wix[k * 256 + nn]
              : (k < 512) ? Wi[(k - 256) * 256 + nn]
                          : Wi[65536 + (k - 512) * 256 + nn];
        } else if (g == 1) {
            v = (k < 256) ? Wux[k * 256 + nn]
              : (k < 512) ? Wu[(k - 256) * 256 + nn]
                          : Wu[65536 + (k - 512) * 256 + nn];
        } else {
            int kf = g - 2;  // f0 / f1
            v = (k < 256) ? Wfx[k * 256 + nn]
              : (k < 512) ? Wf[((kf * 2 + 0) * 256 + (k - 256)) * 256 + nn]
                          : Wf[((kf * 2 + 1) * 256 + (k - 512)) * 256 + nn];
        }
        Wbig[i] = v;
        return;
    }
    i -= 768 * 1024;
    if (i < 1024) {
        int g = i >> 8, nn = i & 255;
        float v;
        if (g == 0)      v = bix[nn] + bi[nn] + bi[256 + nn];
        else if (g == 1) v = bux[nn] + bu[nn] + bu[256 + nn];
        else if (g == 2) v = bfx[nn] + bf[nn] + bf[256 + nn];
        else             v = bfx[nn] + bf[512 + nn] + bf[768 + nn];
        bias_big[i] = v;
        return;
    }
    i -= 1024;
    if (i < 256 * 512) {
        int k = i >> 9, n = i & 511;
        Wleaf[i] = (n < 256) ? Wcx[k * 256 + n] : Wox[k * 256 + (n - 256)];
        return;
    }
    i -= 256 * 512;
    if (i < 512) {
        bias_leaf[i] = (i < 256) ? bcx[i] : box[i - 256];
    }
}

// ---------------------------------------------------------------------------
// Split Wbig into 3 bf16 planes TRANSPOSED: Wt_s[n][k] (1024 x 768).
__global__ __launch_bounds__(256) void split_weights_T(
    const float* __restrict__ Wbig,
    ushort* __restrict__ Wth, ushort* __restrict__ Wtm, ushort* __restrict__ Wtl)
{
    __shared__ float sh[32][33];
    const int k0 = blockIdx.x * 32, n0 = blockIdx.y * 32;
    const int t = threadIdx.x;
    {
        int r = t >> 3, c4 = (t & 7) * 4;
        float4 v = *(const float4*)&Wbig[(size_t)(k0 + r) * 1024 + n0 + c4];
        sh[r][c4] = v.x; sh[r][c4 + 1] = v.y; sh[r][c4 + 2] = v.z; sh[r][c4 + 3] = v.w;
    }
    __syncthreads();
    int n = t >> 3, kc = (t & 7) * 4;
    ushort oh[4], om[4], ol[4];
#pragma unroll
    for (int j = 0; j < 4; ++j)
        split3(sh[kc + j][n], oh[j], om[j], ol[j]);
    size_t o = (size_t)(n0 + n) * 768 + k0 + kc;
    *(ushort4*)&Wth[o] = make_ushort4(oh[0], oh[1], oh[2], oh[3]);
    *(ushort4*)&Wtm[o] = make_ushort4(om[0], om[1], om[2], om[3]);
    *(ushort4*)&Wtl[o] = make_ushort4(ol[0], ol[1], ol[2], ol[3]);
}

// ---------------------------------------------------------------------------
// bf16x3 MFMA level kernel, operand-swapped: A=weights, B=activations.
// grid (8, W): blockIdx.x = gy (XCD-pinned weight slice), blockIdx.y = node.
// Staging lives in NAMED registers (a0..a3, w00..w21) — no address-taken
// locals -> no scratch.
__global__ __launch_bounds__(256, 2) void mfma_level(
    const float* __restrict__ x_embed,
    const float* __restrict__ hChild, const float* __restrict__ cChild,
    const ushort* __restrict__ Wth, const ushort* __restrict__ Wtm,
    const ushort* __restrict__ Wtl,
    const float* __restrict__ bias,
    float* __restrict__ hOut, float* __restrict__ cOut, int nstart)
{
    constexpr int AST = 40;                       // ushort stride per row
    __shared__ __align__(16) ushort Wlds[3][128 * AST];   // weights [n_local][k]
    __shared__ __align__(16) ushort Vlds[3][128 * AST];   // activations [b][k]

    const int tid  = threadIdx.x;
    const int gy   = blockIdx.x;
    const int node = blockIdx.y;
    const int lane = tid & 63, wid = tid >> 6;
    const int ni = wid & 1, bw = wid >> 1;
    const int srow = tid & 127, shalf = tid >> 7; // bank-balanced staging map

    // Activation sources (fp32, split on the fly). Row = batch b = srow.
    const float* aX = x_embed + ((size_t)srow * NNODES + (nstart + node)) * LDIM;
    const float* aL = hChild + ((size_t)(2 * node) * BATCH + srow) * LDIM;
    const float* aR = aL + (size_t)BATCH * LDIM;
    // Weight source: n_local = srow -> phys col = (srow>>5)*256 + gy*32 + (srow&31).
    const size_t nb = (size_t)(((srow >> 5) << 8) + gy * 32 + (srow & 31)) * 768;
    const ushort* w0 = Wth + nb;
    const ushort* w1 = Wtm + nb;
    const ushort* w2 = Wtl + nb;

    f32x4 acc[4][4];  // [gate g][batch tile Nt]
#pragma unroll
    for (int g = 0; g < 4; ++g)
#pragma unroll
        for (int t2 = 0; t2 < 4; ++t2) acc[g][t2] = (f32x4){0.f, 0.f, 0.f, 0.f};

    // staging registers (named scalars/vectors only — never address-taken)
    float4 a0, a1, a2, a3;
    int4 w00, w01, w10, w11, w20, w21;

    auto LOADS = [&](int it) {
        const int seg = it >> 3;
        const int koff = (it & 7) * 32 + shalf * 16;
        const float* ap = (seg == 0) ? aX : (seg == 1) ? aL : aR;
        ap += koff;
        a0 = *(const float4*)(ap);
        a1 = *(const float4*)(ap + 4);
        a2 = *(const float4*)(ap + 8);
        a3 = *(const float4*)(ap + 12);
        const int bko = it * 32 + shalf * 16;
        w00 = *(const int4*)(w0 + bko); w01 = *(const int4*)(w0 + bko + 8);
        w10 = *(const int4*)(w1 + bko); w11 = *(const int4*)(w1 + bko + 8);
        w20 = *(const int4*)(w2 + bko); w21 = *(const int4*)(w2 + bko + 8);
    };
    auto WRITE = [&]() {
        unsigned ph0, pm0, pl0, ph1, pm1, pl1, ph2, pm2, pl2, ph3, pm3, pl3;
        unsigned ph4, pm4, pl4, ph5, pm5, pl5, ph6, pm6, pl6, ph7, pm7, pl7;
        pack2(a0.x, a0.y, ph0, pm0, pl0);
        pack2(a0.z, a0.w, ph1, pm1, pl1);
        pack2(a1.x, a1.y, ph2, pm2, pl2);
        pack2(a1.z, a1.w, ph3, pm3, pl3);
        pack2(a2.x, a2.y, ph4, pm4, pl4);
        pack2(a2.z, a2.w, ph5, pm5, pl5);
        pack2(a3.x, a3.y, ph6, pm6, pl6);
        pack2(a3.z, a3.w, ph7, pm7, pl7);
        const int base = srow * AST + shalf * 16;
        *(int4*)&Vlds[0][base]     = make_int4((int)ph0, (int)ph1, (int)ph2, (int)ph3);
        *(int4*)&Vlds[0][base + 8] = make_int4((int)ph4, (int)ph5, (int)ph6, (int)ph7);
        *(int4*)&Vlds[1][base]     = make_int4((int)pm0, (int)pm1, (int)pm2, (int)pm3);
        *(int4*)&Vlds[1][base + 8] = make_int4((int)pm4, (int)pm5, (int)pm6, (int)pm7);
        *(int4*)&Vlds[2][base]     = make_int4((int)pl0, (int)pl1, (int)pl2, (int)pl3);
        *(int4*)&Vlds[2][base + 8] = make_int4((int)pl4, (int)pl5, (int)pl6, (int)pl7);
        *(int4*)&Wlds[0][base]     = w00;
        *(int4*)&Wlds[0][base + 8] = w01;
        *(int4*)&Wlds[1][base]     = w10;
        *(int4*)&Wlds[1][base + 8] = w11;
        *(int4*)&Wlds[2][base]     = w20;
        *(int4*)&Wlds[2][base + 8] = w21;
    };
    auto COMPUTE = [&]() {
        short8 vf[4][3];   // activation fragments per batch tile (const-indexed)
#pragma unroll
        for (int Nt = 0; Nt < 4; ++Nt) {
            const int rb = (bw * 64 + Nt * 16 + (lane & 15)) * AST + (lane >> 4) * 8;
#pragma unroll
            for (int s = 0; s < 3; ++s) vf[Nt][s] = *(const short8*)&Vlds[s][rb];
        }
#pragma unroll
        for (int g = 0; g < 4; ++g) {
            const int cb = (g * 32 + ni * 16 + (lane & 15)) * AST + (lane >> 4) * 8;
            short8 wh = *(const short8*)&Wlds[0][cb];
            short8 wm = *(const short8*)&Wlds[1][cb];
            short8 wl = *(const short8*)&Wlds[2][cb];
            // small -> large accumulation order
#pragma unroll
            for (int Nt = 0; Nt < 4; ++Nt)
                acc[g][Nt] = __builtin_amdgcn_mfma_f32_16x16x32_bf16(wl, vf[Nt][0], acc[g][Nt], 0, 0, 0);
#pragma unroll
            for (int Nt = 0; Nt < 4; ++Nt)
                acc[g][Nt] = __builtin_amdgcn_mfma_f32_16x16x32_bf16(wh, vf[Nt][2], acc[g][Nt], 0, 0, 0);
#pragma unroll
            for (int Nt = 0; Nt < 4; ++Nt)
                acc[g][Nt] = __builtin_amdgcn_mfma_f32_16x16x32_bf16(wm, vf[Nt][1], acc[g][Nt], 0, 0, 0);
#pragma unroll
            for (int Nt = 0; Nt < 4; ++Nt)
                acc[g][Nt] = __builtin_amdgcn_mfma_f32_16x16x32_bf16(wm, vf[Nt][0], acc[g][Nt], 0, 0, 0);
#pragma unroll
            for (int Nt = 0; Nt < 4; ++Nt)
                acc[g][Nt] = __builtin_amdgcn_mfma_f32_16x16x32_bf16(wh, vf[Nt][1], acc[g][Nt], 0, 0, 0);
#pragma unroll
            for (int Nt = 0; Nt < 4; ++Nt)
                acc[g][Nt] = __builtin_amdgcn_mfma_f32_16x16x32_bf16(wh, vf[Nt][0], acc[g][Nt], 0, 0, 0);
        }
    };

    LOADS(0);
    for (int it = 0; it < 24; ++it) {
        if (it) __syncthreads();
        WRITE();
        __syncthreads();
        if (it + 1 < 24) LOADS(it + 1);
        COMPUTE();
    }

    // ----- fused LSTM epilogue (fp32 c-path, float4 stores) -----
    const int nc = gy * 32 + ni * 16 + ((lane >> 4) << 2);   // out col quad
    const size_t cLb = (size_t)(2 * node) * BATCH * LDIM;
    const size_t cRb = cLb + (size_t)BATCH * LDIM;
    const size_t ob  = (size_t)node * BATCH * LDIM;
    const float4 bi4 = *(const float4*)&bias[nc];
    const float4 bu4 = *(const float4*)&bias[256 + nc];
    const float4 b04 = *(const float4*)&bias[512 + nc];
    const float4 b14 = *(const float4*)&bias[768 + nc];
    const float bi_[4] = {bi4.x, bi4.y, bi4.z, bi4.w};
    const float bu_[4] = {bu4.x, bu4.y, bu4.z, bu4.w};
    const float b0_[4] = {b04.x, b04.y, b04.z, b04.w};
    const float b1_[4] = {b14.x, b14.y, b14.z, b14.w};
#pragma unroll
    for (int Nt = 0; Nt < 4; ++Nt) {
        const int b = bw * 64 + Nt * 16 + (lane & 15);
        float4 cL = *(const float4*)&cChild[cLb + (size_t)b * LDIM + nc];
        float4 cR = *(const float4*)&cChild[cRb + (size_t)b * LDIM + nc];
        float cl4[4] = {cL.x, cL.y, cL.z, cL.w};
        float cr4[4] = {cR.x, cR.y, cR.z, cR.w};
        float4 c4, h4;
        float* cp = (float*)&c4; float* hp = (float*)&h4;
#pragma unroll
        for (int j = 0; j < 4; ++j) {
            float gi = sigmoidf_(acc[0][Nt][j] + bi_[j]);
            float gu = tanhf(acc[1][Nt][j] + bu_[j]);
            float f0 = acc[2][Nt][j] + b0_[j];
            float f1 = acc[3][Nt][j] + b1_[j];
            float c  = gi * gu + f0 * cl4[j] + f1 * cr4[j];
            cp[j] = c;
            hp[j] = tanhf(c);
        }
        *(float4*)&cOut[ob + (size_t)b * LDIM + nc] = c4;
        *(float4*)&hOut[ob + (size_t)b * LDIM + nc] = h4;
    }
}

// ---------------------------------------------------------------------------
// Leaf kernel (round-1/4 proven). grid (1024, 4), block 256.
__global__ __launch_bounds__(256) void leaf_kernel(
    const float* __restrict__ x_embed,
    const float* __restrict__ Wleaf, const float* __restrict__ bias_leaf,
    float* __restrict__ hOut, float* __restrict__ cOut)
{
    __shared__ float As[16 * 68];
    __shared__ float Bs[2 * 16 * 64];
    float acc[2][4][4] = {};
    const int tid = threadIdx.x;
    const int ty = tid >> 4, tx = tid & 15;
    const int row0 = blockIdx.x * 64;
    const int n0 = blockIdx.y * 64;
    const int w = row0 >> 7;
    const int ar = tid >> 2;
    const int kq = (tid & 3) * 4;
    const int b = (row0 + ar) & 127;
    const float* xrow = x_embed + ((size_t)b * NNODES + 511 + w) * LDIM;

    for (int k0 = 0; k0 < 256; k0 += 16) {
        float4 av = *(const float4*)(xrow + k0 + kq);
        As[(kq + 0) * 68 + ar] = av.x;
        As[(kq + 1) * 68 + ar] = av.y;
        As[(kq + 2) * 68 + ar] = av.z;
        As[(kq + 3) * 68 + ar] = av.w;
#pragma unroll
        for (int q = 0; q < 2; ++q) {
            int L = q * 256 + tid;
            int g = L >> 8, kk = (L >> 4) & 15, n4 = (L & 15) * 4;
            float4 bv = *(const float4*)(Wleaf + (size_t)(k0 + kk) * 512 + g * 256 + n0 + n4);
            *(float4*)&Bs[(g * 16 + kk) * 64 + n4] = bv;
        }
        __syncthreads();
#pragma unroll
        for (int kk = 0; kk < 16; ++kk) {
            float4 a = *(const float4*)&As[kk * 68 + ty * 4];
            float av4[4] = {a.x, a.y, a.z, a.w};
#pragma unroll
            for (int g = 0; g < 2; ++g) {
                float4 bb = *(const float4*)&Bs[(g * 16 + kk) * 64 + tx * 4];
                float bv4[4] = {bb.x, bb.y, bb.z, bb.w};
#pragma unroll
                for (int ii = 0; ii < 4; ++ii)
#pragma unroll
                    for (int jj = 0; jj < 4; ++jj)
                        acc[g][ii][jj] += av4[ii] * bv4[jj];
            }
        }
        __syncthreads();
    }
#pragma unroll
    for (int ii = 0; ii < 4; ++ii) {
        int r = row0 + ty * 4 + ii;
        int nc = n0 + tx * 4;
        float4 c4, h4;
        float* cp = (float*)&c4; float* hp = (float*)&h4;
#pragma unroll
        for (int jj = 0; jj < 4; ++jj) {
            int n = nc + jj;
            float ac = acc[0][ii][jj] + bias_leaf[n];
            float ao = acc[1][ii][jj] + bias_leaf[256 + n];
            cp[jj] = ac;
            hp[jj] = sigmoidf_(ao) * tanhf(ac);
        }
        *(float4*)&cOut[(size_t)r * LDIM + nc] = c4;
        *(float4*)&hOut[(size_t)r * LDIM + nc] = h4;
    }
}

// ---------------------------------------------------------------------------
// fp32 level kernel (round-1/4 proven). grid (W*2, 4), block 256.
__global__ __launch_bounds__(256) void level_kernel(
    const float* __restrict__ x_embed,
    const float* __restrict__ hChild, const float* __restrict__ cChild,
    const float* __restrict__ Wbig, const float* __restrict__ bias_big,
    float* __restrict__ hOut, float* __restrict__ cOut,
    int nstart)
{
    __shared__ float As[16 * 68];
    __shared__ float Bs[4 * 16 * 64];
    float acc[4][4][4] = {};
    const int tid = threadIdx.x;
    const int ty = tid >> 4, tx = tid & 15;
    const int row0 = blockIdx.x * 64;
    const int n0 = blockIdx.y * 64;
    const int w = row0 >> 7;
    const int ar = tid >> 2;
    const int kq = (tid & 3) * 4;
    const int b = (row0 + ar) & 127;
    const float* srcX = x_embed + ((size_t)b * NNODES + nstart + w) * LDIM;
    const float* srcL = hChild + ((size_t)(2 * w) * BATCH + b) * LDIM;
    const float* srcR = hChild + ((size_t)(2 * w + 1) * BATCH + b) * LDIM;

    for (int k0 = 0; k0 < 768; k0 += 16) {
        int seg = k0 >> 8, off = k0 & 255;
        const float* src = (seg == 0) ? srcX : (seg == 1) ? srcL : srcR;
        float4 av = *(const float4*)(src + off + kq);
        As[(kq + 0) * 68 + ar] = av.x;
        As[(kq + 1) * 68 + ar] = av.y;
        As[(kq + 2) * 68 + ar] = av.z;
        As[(kq + 3) * 68 + ar] = av.w;
#pragma unroll
        for (int q = 0; q < 4; ++q) {
            int L = q * 256 + tid;
            int g = L >> 8, kk = (L >> 4) & 15, n4 = (L & 15) * 4;
            float4 bv = *(const float4*)(Wbig + (size_t)(k0 + kk) * 1024 + g * 256 + n0 + n4);
            *(float4*)&Bs[(g * 16 + kk) * 64 + n4] = bv;
        }
        __syncthreads();
#pragma unroll
        for (int kk = 0; kk < 16; ++kk) {
            float4 a = *(const float4*)&As[kk * 68 + ty * 4];
            float av4[4] = {a.x, a.y, a.z, a.w};
#pragma unroll
            for (int g = 0; g < 4; ++g) {
                float4 bb = *(const float4*)&Bs[(g * 16 + kk) * 64 + tx * 4];
                float bv4[4] = {bb.x, bb.y, bb.z, bb.w};
#pragma unroll
                for (int ii = 0; ii < 4; ++ii)
#pragma unroll
                    for (int jj = 0; jj < 4; ++jj)
                        acc[g][ii][jj] += av4[ii] * bv4[jj];
            }
        }
        __syncthreads();
    }
    const size_t cLbase = ((size_t)(2 * w) * BATCH) * LDIM;
    const size_t cRbase = ((size_t)(2 * w + 1) * BATCH) * LDIM;
#pragma unroll
    for (int ii = 0; ii < 4; ++ii) {
        int r = row0 + ty * 4 + ii;
        int bb2 = r & 127;
        int nc = n0 + tx * 4;
        float4 cL = *(const float4*)&cChild[cLbase + (size_t)bb2 * LDIM + nc];
        float4 cR = *(const float4*)&cChild[cRbase + (size_t)bb2 * LDIM + nc];
        float cl4[4] = {cL.x, cL.y, cL.z, cL.w};
        float cr4[4] = {cR.x, cR.y, cR.z, cR.w};
        float4 c4, h4;
        float* cp = (float*)&c4; float* hp = (float*)&h4;
#pragma unroll
        for (int jj = 0; jj < 4; ++jj) {
            int n = nc + jj;
            float gi = sigmoidf_(acc[0][ii][jj] + bias_big[n]);
            float gu = tanhf(acc[1][ii][jj] + bias_big[256 + n]);
            float f0 = acc[2][ii][jj] + bias_big[512 + n];
            float f1 = acc[3][ii][jj] + bias_big[768 + n];
            float c = gi * gu + f0 * cl4[jj] + f1 * cr4[jj];
            cp[jj] = c;
            hp[jj] = tanhf(c);
        }
        *(float4*)&cOut[(size_t)r * LDIM + nc] = c4;
        *(float4*)&hOut[(size_t)r * LDIM + nc] = h4;
    }
}

// ---------------------------------------------------------------------------
// Split-K partial (TM=4, one 256-wide K segment per blockIdx.z). grid (W*2,4,3).
__global__ __launch_bounds__(256) void gemm_part4(
    const float* __restrict__ x_embed, const float* __restrict__ hChild,
    const float* __restrict__ Wbig,
    float* __restrict__ part, int nstart, int rowsTotal)
{
    __shared__ float As[16 * 68];
    __shared__ float Bs[4 * 16 * 64];
    float acc[4][4][4] = {};
    const int tid = threadIdx.x;
    const int ty = tid >> 4, tx = tid & 15;
    const int row0 = blockIdx.x * 64;
    const int n0 = blockIdx.y * 64;
    const int seg = blockIdx.z;
    const int w = row0 >> 7;
    const int ar = tid >> 2;
    const int kq = (tid & 3) * 4;
    const int b = (row0 + ar) & 127;
    const float* src =
        (seg == 0) ? x_embed + ((size_t)b * NNODES + nstart + w) * LDIM
                   : hChild + ((size_t)(2 * w + (seg - 1)) * BATCH + b) * LDIM;

    for (int k0 = 0; k0 < 256; k0 += 16) {
        float4 av = *(const float4*)(src + k0 + kq);
        As[(kq + 0) * 68 + ar] = av.x;
        As[(kq + 1) * 68 + ar] = av.y;
        As[(kq + 2) * 68 + ar] = av.z;
        As[(kq + 3) * 68 + ar] = av.w;
#pragma unroll
        for (int q = 0; q < 4; ++q) {
            int L = q * 256 + tid;
            int g = L >> 8, kk = (L >> 4) & 15, n4 = (L & 15) * 4;
            float4 bv = *(const float4*)(Wbig + (size_t)(seg * 256 + k0 + kk) * 1024
                                         + g * 256 + n0 + n4);
            *(float4*)&Bs[(g * 16 + kk) * 64 + n4] = bv;
        }
        __syncthreads();
#pragma unroll
        for (int kk = 0; kk < 16; ++kk) {
            float4 a = *(const float4*)&As[kk * 68 + ty * 4];
            float av4[4] = {a.x, a.y, a.z, a.w};
#pragma unroll
            for (int g = 0; g < 4; ++g) {
                float4 bb = *(const float4*)&Bs[(g * 16 + kk) * 64 + tx * 4];
                float bv4[4] = {bb.x, bb.y, bb.z, bb.w};
#pragma unroll
                for (int ii = 0; ii < 4; ++ii)
#pragma unroll
                    for (int jj = 0; jj < 4; ++jj)
                        acc[g][ii][jj] += av4[ii] * bv4[jj];
            }
        }
        __syncthreads();
    }
#pragma unroll
    for (int ii = 0; ii < 4; ++ii) {
        int r = row0 + ty * 4 + ii;
        size_t base = ((size_t)seg * rowsTotal + r) * 1024 + n0 + tx * 4;
#pragma unroll
        for (int g = 0; g < 4; ++g)
            *(float4*)&part[base + g * 256] = *(float4*)acc[g][ii];
    }
}

// ---------------------------------------------------------------------------
// Combine 3 split-K partials + LSTM epilogue. grid (rows/4), block 256.
__global__ __launch_bounds__(256) void combine_eps(
    const float* __restrict__ part, const float* __restrict__ cChild,
    const float* __restrict__ bias,
    float* __restrict__ hOut, float* __restrict__ cOut, int rowsTotal)
{
    int idx = blockIdx.x * 256 + threadIdx.x;
    int row = idx >> 6, n = (idx & 63) * 4;
    size_t sseg = (size_t)rowsTotal * 1024;
    const float* p0 = part + (size_t)row * 1024 + n;
    float s[4][4];
#pragma unroll
    for (int g = 0; g < 4; ++g) {
        float4 a = *(const float4*)(p0 + g * 256);
        float4 b = *(const float4*)(p0 + sseg + g * 256);
        float4 c = *(const float4*)(p0 + 2 * sseg + g * 256);
        s[g][0] = a.x + b.x + c.x; s[g][1] = a.y + b.y + c.y;
        s[g][2] = a.z + b.z + c.z; s[g][3] = a.w + b.w + c.w;
    }
    int node = row >> 7, b = row & 127;
    float4 cL = *(const float4*)&cChild[((size_t)(2 * node) * BATCH + b) * LDIM + n];
    float4 cR = *(const float4*)&cChild[((size_t)(2 * node + 1) * BATCH + b) * LDIM + n];
    float cl4[4] = {cL.x, cL.y, cL.z, cL.w};
    float cr4[4] = {cR.x, cR.y, cR.z, cR.w};
    float4 c4, h4;
    float* cp = (float*)&c4; float* hp = (float*)&h4;
#pragma unroll
    for (int jj = 0; jj < 4; ++jj) {
        int nn = n + jj;
        float gi = sigmoidf_(s[0][jj] + bias[nn]);
        float gu = tanhf(s[1][jj] + bias[256 + nn]);
        float f0 = s[2][jj] + bias[512 + nn];
        float f1 = s[3][jj] + bias[768 + nn];
        float c = gi * gu + f0 * cl4[jj] + f1 * cr4[jj];
        cp[jj] = c;
        hp[jj] = tanhf(c);
    }
    *(float4*)&cOut[(size_t)row * LDIM + n] = c4;
    *(float4*)&hOut[(size_t)row * LDIM + n] = h4;
}

// ---------------------------------------------------------------------------
// Final: out[b][n] = tanh([init | c_root | h_root] @ Woend + boend). grid 128.
__global__ __launch_bounds__(256) void final_kernel(
    const float* __restrict__ init_emb,
    const float* __restrict__ cRoot, const float* __restrict__ hRoot,
    const float* __restrict__ Woend, const float* __restrict__ boend,
    float* __restrict__ out)
{
    __shared__ float sv[768];
    int b = blockIdx.x, t = threadIdx.x;
    sv[t]       = init_emb[(size_t)b * 256 + t];
    sv[256 + t] = cRoot[(size_t)b * 256 + t];
    sv[512 + t] = hRoot[(size_t)b * 256 + t];
    __syncthreads();
    float acc = boend[t];
#pragma unroll 4
    for (int d = 0; d < 768; ++d)
        acc += sv[d] * Woend[(size_t)d * 256 + t];
    out[(size_t)b * 256 + t] = tanhf(acc);
}

// ---------------------------------------------------------------------------
extern "C" void kernel_launch(void* const* d_in, const int* in_sizes, int n_in,
                              void* d_out, int out_size, void* d_ws, size_t ws_size,
                              hipStream_t stream)
{
    const float* x_embed  = (const float*)d_in[0];
    const float* init_emb = (const float*)d_in[1];
    const float* Wcx = (const float*)d_in[2];  const float* bcx = (const float*)d_in[3];
    const float* Wox = (const float*)d_in[4];  const float* box = (const float*)d_in[5];
    const float* Wix = (const float*)d_in[6];  const float* bix = (const float*)d_in[7];
    const float* Wfx = (const float*)d_in[8];  const float* bfx = (const float*)d_in[9];
    const float* Wux = (const float*)d_in[10]; const float* bux = (const float*)d_in[11];
    const float* Wi  = (const float*)d_in[12]; const float* bi  = (const float*)d_in[13];
    const float* Wf  = (const float*)d_in[14]; const float* bf  = (const float*)d_in[15];
    const float* Wu  = (const float*)d_in[16]; const float* bu  = (const float*)d_in[17];
    const float* Woend = (const float*)d_in[18]; const float* boend = (const float*)d_in[19];
    float* out = (float*)d_out;
    float* ws  = (float*)d_ws;

    size_t off = 0;
    float* hA = ws + off; off += (size_t)512 * 128 * 256;
    float* cA = ws + off; off += (size_t)512 * 128 * 256;
    float* hB = ws + off; off += (size_t)256 * 128 * 256;
    float* cB = ws + off; off += (size_t)256 * 128 * 256;
    float* Wbig      = ws + off; off += (size_t)768 * 1024;
    float* bias_big  = ws + off; off += 1024;
    float* Wleaf     = ws + off; off += (size_t)256 * 512;
    float* bias_leaf = ws + off; off += 512;
    // bf16 weight splits, transposed [n][k]
    ushort* Wth = (ushort*)(ws + off); off += (size_t)768 * 1024 / 2;
    ushort* Wtm = (ushort*)(ws + off); off += (size_t)768 * 1024 / 2;
    ushort* Wtl = (ushort*)(ws + off); off += (size_t)768 * 1024 / 2;
    size_t mfma_need = off * sizeof(float);
    size_t part_off = off;
    float* part = ws + part_off;

    bool mfma_ok = mfma_need <= ws_size;

    {
        int total = 768 * 1024 + 1024 + 256 * 512 + 512;
        int blocks = (total + 255) / 256;
        build_weights<<<blocks, 256, 0, stream>>>(
            Wix, bix, Wfx, bfx, Wux, bux, Wi, bi, Wf, bf, Wu, bu,
            Wcx, bcx, Wox, box, Wbig, bias_big, Wleaf, bias_leaf);
    }
    if (mfma_ok) {
        split_weights_T<<<dim3(24, 32), 256, 0, stream>>>(Wbig, Wth, Wtm, Wtl);
    }

    leaf_kernel<<<dim3(1024, 4), 256, 0, stream>>>(x_embed, Wleaf, bias_leaf, hA, cA);

    float* hbufs[2] = {hA, hB};
    float* cbufs[2] = {cA, cB};
    int child = 0;  // leaves in A
    for (int lvl = 8; lvl >= 0; --lvl) {
        int W = 1 << lvl, s = W - 1;
        int outb = child ^ 1;
        size_t rows = (size_t)W * 128;
        bool split = (W <= 16) &&
                     ((part_off + 3 * rows * 1024) * sizeof(float) <= ws_size);
        if (lvl >= 5 && mfma_ok) {
            mfma_level<<<dim3(8, W), 256, 0, stream>>>(
                x_embed, hbufs[child], cbufs[child], Wth, Wtm, Wtl, bias_big,
                hbufs[outb], cbufs[outb], s);
        } else if (split) {
            gemm_part4<<<dim3(W * 2, 4, 3), 256, 0, stream>>>(
                x_embed, hbufs[child], Wbig, part, s, (int)rows);
            combine_eps<<<(int)(rows / 4), 256, 0, stream>>>(
                part, cbufs[child], bias_big, hbufs[outb], cbufs[outb], (int)rows);
        } else {
            level_kernel<<<dim3(W * 2, 4), 256, 0, stream>>>(
                x_embed, hbufs[child], cbufs[child], Wbig, bias_big,
                hbufs[outb], cbufs[outb], s);
        }
        child = outb;
    }

    final_kernel<<<128, 256, 0, stream>>>(init_emb, cbufs[child], hbufs[child],
                                          Woend, boend, out);
}

// Round 9
// 1271.738 us; speedup vs baseline: 1.8832x; 1.8832x over previous
//
#include <hip/hip_runtime.h>
#include <hip/hip_bf16.h>
#include <math.h>

// Tree-LSTM "LogicEncoder": D=10, N=1023 nodes, B=128, LD=256, K=2.
// Round 9: two changes to mfma_level.
//  1. De-lambda: staging via textual macro + inline WRITE/COMPUTE. The
//     LOADS/WRITE lambdas' by-reference captures were address-exposing the
//     staging values (2.06 GB WRITE == 160 staged B/thread/iter x 24 x 524K
//     threads, invariant across 4 staging implementations) — a non-inlined
//     lambda forces captures to scratch no matter how they're declared.
//  2. Grid (W, 8) node-fastest: node%8 -> XCD, the 8 gy blocks of one node
//     share an XCD L2 -> activations fetched ~1x (was 8x = 805 MB).
// Leaf + levels 4..0 keep the round-4 proven fp32 kernels.

#define NNODES 1023
#define BATCH  128
#define LDIM   256

typedef __attribute__((ext_vector_type(8))) short short8;
typedef __attribute__((ext_vector_type(4))) float f32x4;

__device__ __forceinline__ float sigmoidf_(float x) {
    return 1.f / (1.f + expf(-x));
}

// fp32 -> 3x bf16, round-to-nearest-even at each stage; residuals exact.
__device__ __forceinline__ void split3(float x, ushort& h, ushort& m, ushort& l) {
    unsigned u = __float_as_uint(x);
    unsigned hu = (u + 0x7FFFu + ((u >> 16) & 1u)) & 0xFFFF0000u;
    h = (ushort)(hu >> 16);
    float r = x - __uint_as_float(hu);
    unsigned ur = __float_as_uint(r);
    unsigned mu = (ur + 0x7FFFu + ((ur >> 16) & 1u)) & 0xFFFF0000u;
    m = (ushort)(mu >> 16);
    float r2 = r - __uint_as_float(mu);
    unsigned u2 = __float_as_uint(r2);
    l = (ushort)((u2 + 0x7FFFu + ((u2 >> 16) & 1u)) >> 16);
}

// pair-split, BY-VALUE result (no reference outputs anywhere in the hot path)
struct P3 { unsigned h, m, l; };
__device__ __forceinline__ P3 pack2v(float x0, float x1) {
    ushort h0, m0, l0, h1, m1, l1;
    split3(x0, h0, m0, l0);
    split3(x1, h1, m1, l1);
    P3 r;
    r.h = (unsigned)h0 | ((unsigned)h1 << 16);
    r.m = (unsigned)m0 | ((unsigned)m1 << 16);
    r.l = (unsigned)l0 | ((unsigned)l1 << 16);
    return r;
}

// ---------------------------------------------------------------------------
// Pack Wbig (768x1024) + bias_big(1024) + Wleaf(256x512) + bias_leaf(512).
__global__ __launch_bounds__(256) void build_weights(
    const float* __restrict__ Wix, const float* __restrict__ bix,
    const float* __restrict__ Wfx, const float* __restrict__ bfx,
    const float* __restrict__ Wux, const float* __restrict__ bux,
    const float* __restrict__ Wi,  const float* __restrict__ bi,
    const float* __restrict__ Wf,  const float* __restrict__ bf,
    const float* __restrict__ Wu,  const float* __restrict__ bu,
    const float* __restrict__ Wcx, const float* __restrict__ bcx,
    const float* __restrict__ Wox, const float* __restrict__ box,
    float* __restrict__ Wbig, float* __restrict__ bias_big,
    float* __restrict__ Wleaf, float* __restrict__ bias_leaf)
{
    int i = blockIdx.x * blockDim.x + threadIdx.x;
    if (i < 768 * 1024) {
        int k = i >> 10, n = i & 1023;
        int g = n >> 8, nn = n & 255;
        float v;
        if (g == 0) {
            v = (k < 256) ? Wix[k * 256 + nn]
              : (k < 512) ? Wi[(k - 256) * 256 + nn]
                          : Wi[65536 + (k - 512) * 256 + nn];
        } else if (g == 1) {
            v = (k < 256) ? Wux[k * 256 + nn]
              : (k < 512) ? Wu[(k - 256) * 256 + nn]
                          : Wu[65536 + (k - 512) * 256 + nn];
        } else {
            int kf = g - 2;  // f0 / f1
            v = (k < 256) ? Wfx[k * 256 + nn]
              : (k < 512) ? Wf[((kf * 2 + 0) * 256 + (k - 256)) * 256 + nn]
                          : Wf[((kf * 2 + 1) * 256 + (k - 512)) * 256 + nn];
        }
        Wbig[i] = v;
        return;
    }
    i -= 768 * 1024;
    if (i < 1024) {
        int g = i >> 8, nn = i & 255;
        float v;
        if (g == 0)      v = bix[nn] + bi[nn] + bi[256 + nn];
        else if (g == 1) v = bux[nn] + bu[nn] + bu[256 + nn];
        else if (g == 2) v = bfx[nn] + bf[nn] + bf[256 + nn];
        else             v = bfx[nn] + bf[512 + nn] + bf[768 + nn];
        bias_big[i] = v;
        return;
    }
    i -= 1024;
    if (i < 256 * 512) {
        int k = i >> 9, n = i & 511;
        Wleaf[i] = (n < 256) ? Wcx[k * 256 + n] : Wox[k * 256 + (n - 256)];
        return;
    }
    i -= 256 * 512;
    if (i < 512) {
        bias_leaf[i] = (i < 256) ? bcx[i] : box[i - 256];
    }
}

// ---------------------------------------------------------------------------
// Split Wbig into 3 bf16 planes TRANSPOSED: Wt_s[n][k] (1024 x 768).
__global__ __launch_bounds__(256) void split_weights_T(
    const float* __restrict__ Wbig,
    ushort* __restrict__ Wth, ushort* __restrict__ Wtm, ushort* __restrict__ Wtl)
{
    __shared__ float sh[32][33];
    const int k0 = blockIdx.x * 32, n0 = blockIdx.y * 32;
    const int t = threadIdx.x;
    {
        int r = t >> 3, c4 = (t & 7) * 4;
        float4 v = *(const float4*)&Wbig[(size_t)(k0 + r) * 1024 + n0 + c4];
        sh[r][c4] = v.x; sh[r][c4 + 1] = v.y; sh[r][c4 + 2] = v.z; sh[r][c4 + 3] = v.w;
    }
    __syncthreads();
    int n = t >> 3, kc = (t & 7) * 4;
    ushort oh[4], om[4], ol[4];
#pragma unroll
    for (int j = 0; j < 4; ++j)
        split3(sh[kc + j][n], oh[j], om[j], ol[j]);
    size_t o = (size_t)(n0 + n) * 768 + k0 + kc;
    *(ushort4*)&Wth[o] = make_ushort4(oh[0], oh[1], oh[2], oh[3]);
    *(ushort4*)&Wtm[o] = make_ushort4(om[0], om[1], om[2], om[3]);
    *(ushort4*)&Wtl[o] = make_ushort4(ol[0], ol[1], ol[2], ol[3]);
}

// ---------------------------------------------------------------------------
// bf16x3 MFMA level kernel, operand-swapped: A=weights, B=activations.
// grid (W, 8): blockIdx.x = node (fastest -> node%8 = XCD, so the 8 gy blocks
// of a node share one XCD's L2 -> activations fetched once), blockIdx.y = gy.
// NO lambdas: staging is a textual macro into named registers; WRITE and
// COMPUTE are inline in the loop body.
__global__ __launch_bounds__(256, 2) void mfma_level(
    const float* __restrict__ x_embed,
    const float* __restrict__ hChild, const float* __restrict__ cChild,
    const ushort* __restrict__ Wth, const ushort* __restrict__ Wtm,
    const ushort* __restrict__ Wtl,
    const float* __restrict__ bias,
    float* __restrict__ hOut, float* __restrict__ cOut, int nstart)
{
    constexpr int AST = 40;                       // ushort stride per row
    __shared__ __align__(16) ushort Wlds[3][128 * AST];   // weights [n_local][k]
    __shared__ __align__(16) ushort Vlds[3][128 * AST];   // activations [b][k]

    const int tid  = threadIdx.x;
    const int node = blockIdx.x;                  // fastest -> XCD-pinned node
    const int gy   = blockIdx.y;
    const int lane = tid & 63, wid = tid >> 6;
    const int ni = wid & 1, bw = wid >> 1;
    const int srow = tid & 127, shalf = tid >> 7; // bank-balanced staging map

    // Activation sources (fp32, split on the fly). Row = batch b = srow.
    const float* aX = x_embed + ((size_t)srow * NNODES + (nstart + node)) * LDIM;
    const float* aL = hChild + ((size_t)(2 * node) * BATCH + srow) * LDIM;
    const float* aR = aL + (size_t)BATCH * LDIM;
    // Weight source: n_local = srow -> phys col = (srow>>5)*256 + gy*32 + (srow&31).
    const size_t nb = (size_t)(((srow >> 5) << 8) + gy * 32 + (srow & 31)) * 768;
    const ushort* w0 = Wth + nb;
    const ushort* w1 = Wtm + nb;
    const ushort* w2 = Wtl + nb;

    f32x4 acc[4][4];  // [gate g][batch tile Nt]
#pragma unroll
    for (int g = 0; g < 4; ++g)
#pragma unroll
        for (int t2 = 0; t2 < 4; ++t2) acc[g][t2] = (f32x4){0.f, 0.f, 0.f, 0.f};

    // staging registers — named, never address-taken, written only by macro
    float4 a0, a1, a2, a3;
    int4 w00, w01, w10, w11, w20, w21;

#define TREE_LOADS(IT)                                                         \
    {                                                                          \
        const int seg_  = (IT) >> 3;                                           \
        const int koff_ = ((IT) & 7) * 32 + shalf * 16;                        \
        const float* ap_ = (seg_ == 0) ? aX : (seg_ == 1) ? aL : aR;           \
        ap_ += koff_;                                                          \
        a0 = *(const float4*)(ap_);                                            \
        a1 = *(const float4*)(ap_ + 4);                                        \
        a2 = *(const float4*)(ap_ + 8);                                        \
        a3 = *(const float4*)(ap_ + 12);                                       \
        const int bko_ = (IT) * 32 + shalf * 16;                               \
        w00 = *(const int4*)(w0 + bko_); w01 = *(const int4*)(w0 + bko_ + 8);  \
        w10 = *(const int4*)(w1 + bko_); w11 = *(const int4*)(w1 + bko_ + 8);  \
        w20 = *(const int4*)(w2 + bko_); w21 = *(const int4*)(w2 + bko_ + 8);  \
    }

    TREE_LOADS(0);
    for (int it = 0; it < 24; ++it) {
        if (it) __syncthreads();
        // ---- WRITE (inline): pack staged activations, store both LDS tiles --
        {
            P3 p0 = pack2v(a0.x, a0.y), p1 = pack2v(a0.z, a0.w);
            P3 p2 = pack2v(a1.x, a1.y), p3 = pack2v(a1.z, a1.w);
            P3 p4 = pack2v(a2.x, a2.y), p5 = pack2v(a2.z, a2.w);
            P3 p6 = pack2v(a3.x, a3.y), p7 = pack2v(a3.z, a3.w);
            const int base = srow * AST + shalf * 16;
            *(int4*)&Vlds[0][base]     = make_int4((int)p0.h, (int)p1.h, (int)p2.h, (int)p3.h);
            *(int4*)&Vlds[0][base + 8] = make_int4((int)p4.h, (int)p5.h, (int)p6.h, (int)p7.h);
            *(int4*)&Vlds[1][base]     = make_int4((int)p0.m, (int)p1.m, (int)p2.m, (int)p3.m);
            *(int4*)&Vlds[1][base + 8] = make_int4((int)p4.m, (int)p5.m, (int)p6.m, (int)p7.m);
            *(int4*)&Vlds[2][base]     = make_int4((int)p0.l, (int)p1.l, (int)p2.l, (int)p3.l);
            *(int4*)&Vlds[2][base + 8] = make_int4((int)p4.l, (int)p5.l, (int)p6.l, (int)p7.l);
            *(int4*)&Wlds[0][base]     = w00;
            *(int4*)&Wlds[0][base + 8] = w01;
            *(int4*)&Wlds[1][base]     = w10;
            *(int4*)&Wlds[1][base + 8] = w11;
            *(int4*)&Wlds[2][base]     = w20;
            *(int4*)&Wlds[2][base + 8] = w21;
        }
        __syncthreads();
        if (it + 1 < 24) TREE_LOADS(it + 1);   // prefetch next K-step
        // ---- COMPUTE (inline): 96 MFMAs, small->large accumulation order ----
        {
            short8 vf[4][3];   // static-indexed (fully unrolled) -> registers
#pragma unroll
            for (int Nt = 0; Nt < 4; ++Nt) {
                const int rb = (bw * 64 + Nt * 16 + (lane & 15)) * AST + (lane >> 4) * 8;
#pragma unroll
                for (int s = 0; s < 3; ++s) vf[Nt][s] = *(const short8*)&Vlds[s][rb];
            }
#pragma unroll
            for (int g = 0; g < 4; ++g) {
                const int cb = (g * 32 + ni * 16 + (lane & 15)) * AST + (lane >> 4) * 8;
                short8 wh = *(const short8*)&Wlds[0][cb];
                short8 wm = *(const short8*)&Wlds[1][cb];
                short8 wl = *(const short8*)&Wlds[2][cb];
#pragma unroll
                for (int Nt = 0; Nt < 4; ++Nt)
                    acc[g][Nt] = __builtin_amdgcn_mfma_f32_16x16x32_bf16(wl, vf[Nt][0], acc[g][Nt], 0, 0, 0);
#pragma unroll
                for (int Nt = 0; Nt < 4; ++Nt)
                    acc[g][Nt] = __builtin_amdgcn_mfma_f32_16x16x32_bf16(wh, vf[Nt][2], acc[g][Nt], 0, 0, 0);
#pragma unroll
                for (int Nt = 0; Nt < 4; ++Nt)
                    acc[g][Nt] = __builtin_amdgcn_mfma_f32_16x16x32_bf16(wm, vf[Nt][1], acc[g][Nt], 0, 0, 0);
#pragma unroll
                for (int Nt = 0; Nt < 4; ++Nt)
                    acc[g][Nt] = __builtin_amdgcn_mfma_f32_16x16x32_bf16(wm, vf[Nt][0], acc[g][Nt], 0, 0, 0);
#pragma unroll
                for (int Nt = 0; Nt < 4; ++Nt)
                    acc[g][Nt] = __builtin_amdgcn_mfma_f32_16x16x32_bf16(wh, vf[Nt][1], acc[g][Nt], 0, 0, 0);
#pragma unroll
                for (int Nt = 0; Nt < 4; ++Nt)
                    acc[g][Nt] = __builtin_amdgcn_mfma_f32_16x16x32_bf16(wh, vf[Nt][0], acc[g][Nt], 0, 0, 0);
            }
        }
    }
#undef TREE_LOADS

    // ----- fused LSTM epilogue (fp32 c-path, float4 stores) -----
    const int nc = gy * 32 + ni * 16 + ((lane >> 4) << 2);   // out col quad
    const size_t cLb = (size_t)(2 * node) * BATCH * LDIM;
    const size_t cRb = cLb + (size_t)BATCH * LDIM;
    const size_t ob  = (size_t)node * BATCH * LDIM;
    const float4 bi4 = *(const float4*)&bias[nc];
    const float4 bu4 = *(const float4*)&bias[256 + nc];
    const float4 b04 = *(const float4*)&bias[512 + nc];
    const float4 b14 = *(const float4*)&bias[768 + nc];
    const float bi_[4] = {bi4.x, bi4.y, bi4.z, bi4.w};
    const float bu_[4] = {bu4.x, bu4.y, bu4.z, bu4.w};
    const float b0_[4] = {b04.x, b04.y, b04.z, b04.w};
    const float b1_[4] = {b14.x, b14.y, b14.z, b14.w};
#pragma unroll
    for (int Nt = 0; Nt < 4; ++Nt) {
        const int b = bw * 64 + Nt * 16 + (lane & 15);
        float4 cL = *(const float4*)&cChild[cLb + (size_t)b * LDIM + nc];
        float4 cR = *(const float4*)&cChild[cRb + (size_t)b * LDIM + nc];
        float cl4[4] = {cL.x, cL.y, cL.z, cL.w};
        float cr4[4] = {cR.x, cR.y, cR.z, cR.w};
        float4 c4, h4;
        float* cp = (float*)&c4; float* hp = (float*)&h4;
#pragma unroll
        for (int j = 0; j < 4; ++j) {
            float gi = sigmoidf_(acc[0][Nt][j] + bi_[j]);
            float gu = tanhf(acc[1][Nt][j] + bu_[j]);
            float f0 = acc[2][Nt][j] + b0_[j];
            float f1 = acc[3][Nt][j] + b1_[j];
            float c  = gi * gu + f0 * cl4[j] + f1 * cr4[j];
            cp[j] = c;
            hp[j] = tanhf(c);
        }
        *(float4*)&cOut[ob + (size_t)b * LDIM + nc] = c4;
        *(float4*)&hOut[ob + (size_t)b * LDIM + nc] = h4;
    }
}

// ---------------------------------------------------------------------------
// Leaf kernel (round-1/4 proven). grid (1024, 4), block 256.
__global__ __launch_bounds__(256) void leaf_kernel(
    const float* __restrict__ x_embed,
    const float* __restrict__ Wleaf, const float* __restrict__ bias_leaf,
    float* __restrict__ hOut, float* __restrict__ cOut)
{
    __shared__ float As[16 * 68];
    __shared__ float Bs[2 * 16 * 64];
    float acc[2][4][4] = {};
    const int tid = threadIdx.x;
    const int ty = tid >> 4, tx = tid & 15;
    const int row0 = blockIdx.x * 64;
    const int n0 = blockIdx.y * 64;
    const int w = row0 >> 7;
    const int ar = tid >> 2;
    const int kq = (tid & 3) * 4;
    const int b = (row0 + ar) & 127;
    const float* xrow = x_embed + ((size_t)b * NNODES + 511 + w) * LDIM;

    for (int k0 = 0; k0 < 256; k0 += 16) {
        float4 av = *(const float4*)(xrow + k0 + kq);
        As[(kq + 0) * 68 + ar] = av.x;
        As[(kq + 1) * 68 + ar] = av.y;
        As[(kq + 2) * 68 + ar] = av.z;
        As[(kq + 3) * 68 + ar] = av.w;
#pragma unroll
        for (int q = 0; q < 2; ++q) {
            int L = q * 256 + tid;
            int g = L >> 8, kk = (L >> 4) & 15, n4 = (L & 15) * 4;
            float4 bv = *(const float4*)(Wleaf + (size_t)(k0 + kk) * 512 + g * 256 + n0 + n4);
            *(float4*)&Bs[(g * 16 + kk) * 64 + n4] = bv;
        }
        __syncthreads();
#pragma unroll
        for (int kk = 0; kk < 16; ++kk) {
            float4 a = *(const float4*)&As[kk * 68 + ty * 4];
            float av4[4] = {a.x, a.y, a.z, a.w};
#pragma unroll
            for (int g = 0; g < 2; ++g) {
                float4 bb = *(const float4*)&Bs[(g * 16 + kk) * 64 + tx * 4];
                float bv4[4] = {bb.x, bb.y, bb.z, bb.w};
#pragma unroll
                for (int ii = 0; ii < 4; ++ii)
#pragma unroll
                    for (int jj = 0; jj < 4; ++jj)
                        acc[g][ii][jj] += av4[ii] * bv4[jj];
            }
        }
        __syncthreads();
    }
#pragma unroll
    for (int ii = 0; ii < 4; ++ii) {
        int r = row0 + ty * 4 + ii;
        int nc = n0 + tx * 4;
        float4 c4, h4;
        float* cp = (float*)&c4; float* hp = (float*)&h4;
#pragma unroll
        for (int jj = 0; jj < 4; ++jj) {
            int n = nc + jj;
            float ac = acc[0][ii][jj] + bias_leaf[n];
            float ao = acc[1][ii][jj] + bias_leaf[256 + n];
            cp[jj] = ac;
            hp[jj] = sigmoidf_(ao) * tanhf(ac);
        }
        *(float4*)&cOut[(size_t)r * LDIM + nc] = c4;
        *(float4*)&hOut[(size_t)r * LDIM + nc] = h4;
    }
}

// ---------------------------------------------------------------------------
// fp32 level kernel (round-1/4 proven). grid (W*2, 4), block 256.
__global__ __launch_bounds__(256) void level_kernel(
    const float* __restrict__ x_embed,
    const float* __restrict__ hChild, const float* __restrict__ cChild,
    const float* __restrict__ Wbig, const float* __restrict__ bias_big,
    float* __restrict__ hOut, float* __restrict__ cOut,
    int nstart)
{
    __shared__ float As[16 * 68];
    __shared__ float Bs[4 * 16 * 64];
    float acc[4][4][4] = {};
    const int tid = threadIdx.x;
    const int ty = tid >> 4, tx = tid & 15;
    const int row0 = blockIdx.x * 64;
    const int n0 = blockIdx.y * 64;
    const int w = row0 >> 7;
    const int ar = tid >> 2;
    const int kq = (tid & 3) * 4;
    const int b = (row0 + ar) & 127;
    const float* srcX = x_embed + ((size_t)b * NNODES + nstart + w) * LDIM;
    const float* srcL = hChild + ((size_t)(2 * w) * BATCH + b) * LDIM;
    const float* srcR = hChild + ((size_t)(2 * w + 1) * BATCH + b) * LDIM;

    for (int k0 = 0; k0 < 768; k0 += 16) {
        int seg = k0 >> 8, off = k0 & 255;
        const float* src = (seg == 0) ? srcX : (seg == 1) ? srcL : srcR;
        float4 av = *(const float4*)(src + off + kq);
        As[(kq + 0) * 68 + ar] = av.x;
        As[(kq + 1) * 68 + ar] = av.y;
        As[(kq + 2) * 68 + ar] = av.z;
        As[(kq + 3) * 68 + ar] = av.w;
#pragma unroll
        for (int q = 0; q < 4; ++q) {
            int L = q * 256 + tid;
            int g = L >> 8, kk = (L >> 4) & 15, n4 = (L & 15) * 4;
            float4 bv = *(const float4*)(Wbig + (size_t)(k0 + kk) * 1024 + g * 256 + n0 + n4);
            *(float4*)&Bs[(g * 16 + kk) * 64 + n4] = bv;
        }
        __syncthreads();
#pragma unroll
        for (int kk = 0; kk < 16; ++kk) {
            float4 a = *(const float4*)&As[kk * 68 + ty * 4];
            float av4[4] = {a.x, a.y, a.z, a.w};
#pragma unroll
            for (int g = 0; g < 4; ++g) {
                float4 bb = *(const float4*)&Bs[(g * 16 + kk) * 64 + tx * 4];
                float bv4[4] = {bb.x, bb.y, bb.z, bb.w};
#pragma unroll
                for (int ii = 0; ii < 4; ++ii)
#pragma unroll
                    for (int jj = 0; jj < 4; ++jj)
                        acc[g][ii][jj] += av4[ii] * bv4[jj];
            }
        }
        __syncthreads();
    }
    const size_t cLbase = ((size_t)(2 * w) * BATCH) * LDIM;
    const size_t cRbase = ((size_t)(2 * w + 1) * BATCH) * LDIM;
#pragma unroll
    for (int ii = 0; ii < 4; ++ii) {
        int r = row0 + ty * 4 + ii;
        int bb2 = r & 127;
        int nc = n0 + tx * 4;
        float4 cL = *(const float4*)&cChild[cLbase + (size_t)bb2 * LDIM + nc];
        float4 cR = *(const float4*)&cChild[cRbase + (size_t)bb2 * LDIM + nc];
        float cl4[4] = {cL.x, cL.y, cL.z, cL.w};
        float cr4[4] = {cR.x, cR.y, cR.z, cR.w};
        float4 c4, h4;
        float* cp = (float*)&c4; float* hp = (float*)&h4;
#pragma unroll
        for (int jj = 0; jj < 4; ++jj) {
            int n = nc + jj;
            float gi = sigmoidf_(acc[0][ii][jj] + bias_big[n]);
            float gu = tanhf(acc[1][ii][jj] + bias_big[256 + n]);
            float f0 = acc[2][ii][jj] + bias_big[512 + n];
            float f1 = acc[3][ii][jj] + bias_big[768 + n];
            float c = gi * gu + f0 * cl4[jj] + f1 * cr4[jj];
            cp[jj] = c;
            hp[jj] = tanhf(c);
        }
        *(float4*)&cOut[(size_t)r * LDIM + nc] = c4;
        *(float4*)&hOut[(size_t)r * LDIM + nc] = h4;
    }
}

// ---------------------------------------------------------------------------
// Split-K partial (TM=4, one 256-wide K segment per blockIdx.z). grid (W*2,4,3).
__global__ __launch_bounds__(256) void gemm_part4(
    const float* __restrict__ x_embed, const float* __restrict__ hChild,
    const float* __restrict__ Wbig,
    float* __restrict__ part, int nstart, int rowsTotal)
{
    __shared__ float As[16 * 68];
    __shared__ float Bs[4 * 16 * 64];
    float acc[4][4][4] = {};
    const int tid = threadIdx.x;
    const int ty = tid >> 4, tx = tid & 15;
    const int row0 = blockIdx.x * 64;
    const int n0 = blockIdx.y * 64;
    const int seg = blockIdx.z;
    const int w = row0 >> 7;
    const int ar = tid >> 2;
    const int kq = (tid & 3) * 4;
    const int b = (row0 + ar) & 127;
    const float* src =
        (seg == 0) ? x_embed + ((size_t)b * NNODES + nstart + w) * LDIM
                   : hChild + ((size_t)(2 * w + (seg - 1)) * BATCH + b) * LDIM;

    for (int k0 = 0; k0 < 256; k0 += 16) {
        float4 av = *(const float4*)(src + k0 + kq);
        As[(kq + 0) * 68 + ar] = av.x;
        As[(kq + 1) * 68 + ar] = av.y;
        As[(kq + 2) * 68 + ar] = av.z;
        As[(kq + 3) * 68 + ar] = av.w;
#pragma unroll
        for (int q = 0; q < 4; ++q) {
            int L = q * 256 + tid;
            int g = L >> 8, kk = (L >> 4) & 15, n4 = (L & 15) * 4;
            float4 bv = *(const float4*)(Wbig + (size_t)(seg * 256 + k0 + kk) * 1024
                                         + g * 256 + n0 + n4);
            *(float4*)&Bs[(g * 16 + kk) * 64 + n4] = bv;
        }
        __syncthreads();
#pragma unroll
        for (int kk = 0; kk < 16; ++kk) {
            float4 a = *(const float4*)&As[kk * 68 + ty * 4];
            float av4[4] = {a.x, a.y, a.z, a.w};
#pragma unroll
            for (int g = 0; g < 4; ++g) {
                float4 bb = *(const float4*)&Bs[(g * 16 + kk) * 64 + tx * 4];
                float bv4[4] = {bb.x, bb.y, bb.z, bb.w};
#pragma unroll
                for (int ii = 0; ii < 4; ++ii)
#pragma unroll
                    for (int jj = 0; jj < 4; ++jj)
                        acc[g][ii][jj] += av4[ii] * bv4[jj];
            }
        }
        __syncthreads();
    }
#pragma unroll
    for (int ii = 0; ii < 4; ++ii) {
        int r = row0 + ty * 4 + ii;
        size_t base = ((size_t)seg * rowsTotal + r) * 1024 + n0 + tx * 4;
#pragma unroll
        for (int g = 0; g < 4; ++g)
            *(float4*)&part[base + g * 256] = *(float4*)acc[g][ii];
    }
}

// ---------------------------------------------------------------------------
// Combine 3 split-K partials + LSTM epilogue. grid (rows/4), block 256.
__global__ __launch_bounds__(256) void combine_eps(
    const float* __restrict__ part, const float* __restrict__ cChild,
    const float* __restrict__ bias,
    float* __restrict__ hOut, float* __restrict__ cOut, int rowsTotal)
{
    int idx = blockIdx.x * 256 + threadIdx.x;
    int row = idx >> 6, n = (idx & 63) * 4;
    size_t sseg = (size_t)rowsTotal * 1024;
    const float* p0 = part + (size_t)row * 1024 + n;
    float s[4][4];
#pragma unroll
    for (int g = 0; g < 4; ++g) {
        float4 a = *(const float4*)(p0 + g * 256);
        float4 b = *(const float4*)(p0 + sseg + g * 256);
        float4 c = *(const float4*)(p0 + 2 * sseg + g * 256);
        s[g][0] = a.x + b.x + c.x; s[g][1] = a.y + b.y + c.y;
        s[g][2] = a.z + b.z + c.z; s[g][3] = a.w + b.w + c.w;
    }
    int node = row >> 7, b = row & 127;
    float4 cL = *(const float4*)&cChild[((size_t)(2 * node) * BATCH + b) * LDIM + n];
    float4 cR = *(const float4*)&cChild[((size_t)(2 * node + 1) * BATCH + b) * LDIM + n];
    float cl4[4] = {cL.x, cL.y, cL.z, cL.w};
    float cr4[4] = {cR.x, cR.y, cR.z, cR.w};
    float4 c4, h4;
    float* cp = (float*)&c4; float* hp = (float*)&h4;
#pragma unroll
    for (int jj = 0; jj < 4; ++jj) {
        int nn = n + jj;
        float gi = sigmoidf_(s[0][jj] + bias[nn]);
        float gu = tanhf(s[1][jj] + bias[256 + nn]);
        float f0 = s[2][jj] + bias[512 + nn];
        float f1 = s[3][jj] + bias[768 + nn];
        float c = gi * gu + f0 * cl4[jj] + f1 * cr4[jj];
        cp[jj] = c;
        hp[jj] = tanhf(c);
    }
    *(float4*)&cOut[(size_t)row * LDIM + n] = c4;
    *(float4*)&hOut[(size_t)row * LDIM + n] = h4;
}

// ---------------------------------------------------------------------------
// Final: out[b][n] = tanh([init | c_root | h_root] @ Woend + boend). grid 128.
__global__ __launch_bounds__(256) void final_kernel(
    const float* __restrict__ init_emb,
    const float* __restrict__ cRoot, const float* __restrict__ hRoot,
    const float* __restrict__ Woend, const float* __restrict__ boend,
    float* __restrict__ out)
{
    __shared__ float sv[768];
    int b = blockIdx.x, t = threadIdx.x;
    sv[t]       = init_emb[(size_t)b * 256 + t];
    sv[256 + t] = cRoot[(size_t)b * 256 + t];
    sv[512 + t] = hRoot[(size_t)b * 256 + t];
    __syncthreads();
    float acc = boend[t];
#pragma unroll 4
    for (int d = 0; d < 768; ++d)
        acc += sv[d] * Woend[(size_t)d * 256 + t];
    out[(size_t)b * 256 + t] = tanhf(acc);
}

// ---------------------------------------------------------------------------
extern "C" void kernel_launch(void* const* d_in, const int* in_sizes, int n_in,
                              void* d_out, int out_size, void* d_ws, size_t ws_size,
                              hipStream_t stream)
{
    const float* x_embed  = (const float*)d_in[0];
    const float* init_emb = (const float*)d_in[1];
    const float* Wcx = (const float*)d_in[2];  const float* bcx = (const float*)d_in[3];
    const float* Wox = (const float*)d_in[4];  const float* box = (const float*)d_in[5];
    const float* Wix = (const float*)d_in[6];  const float* bix = (const float*)d_in[7];
    const float* Wfx = (const float*)d_in[8];  const float* bfx = (const float*)d_in[9];
    const float* Wux = (const float*)d_in[10]; const float* bux = (const float*)d_in[11];
    const float* Wi  = (const float*)d_in[12]; const float* bi  = (const float*)d_in[13];
    const float* Wf  = (const float*)d_in[14]; const float* bf  = (const float*)d_in[15];
    const float* Wu  = (const float*)d_in[16]; const float* bu  = (const float*)d_in[17];
    const float* Woend = (const float*)d_in[18]; const float* boend = (const float*)d_in[19];
    float* out = (float*)d_out;
    float* ws  = (float*)d_ws;

    size_t off = 0;
    float* hA = ws + off; off += (size_t)512 * 128 * 256;
    float* cA = ws + off; off += (size_t)512 * 128 * 256;
    float* hB = ws + off; off += (size_t)256 * 128 * 256;
    float* cB = ws + off; off += (size_t)256 * 128 * 256;
    float* Wbig      = ws + off; off += (size_t)768 * 1024;
    float* bias_big  = ws + off; off += 1024;
    float* Wleaf     = ws + off; off += (size_t)256 * 512;
    float* bias_leaf = ws + off; off += 512;
    // bf16 weight splits, transposed [n][k]
    ushort* Wth = (ushort*)(ws + off); off += (size_t)768 * 1024 / 2;
    ushort* Wtm = (ushort*)(ws + off); off += (size_t)768 * 1024 / 2;
    ushort* Wtl = (ushort*)(ws + off); off += (size_t)768 * 1024 / 2;
    size_t mfma_need = off * sizeof(float);
    size_t part_off = off;
    float* part = ws + part_off;

    bool mfma_ok = mfma_need <= ws_size;

    {
        int total = 768 * 1024 + 1024 + 256 * 512 + 512;
        int blocks = (total + 255) / 256;
        build_weights<<<blocks, 256, 0, stream>>>(
            Wix, bix, Wfx, bfx, Wux, bux, Wi, bi, Wf, bf, Wu, bu,
            Wcx, bcx, Wox, box, Wbig, bias_big, Wleaf, bias_leaf);
    }
    if (mfma_ok) {
        split_weights_T<<<dim3(24, 32), 256, 0, stream>>>(Wbig, Wth, Wtm, Wtl);
    }

    leaf_kernel<<<dim3(1024, 4), 256, 0, stream>>>(x_embed, Wleaf, bias_leaf, hA, cA);

    float* hbufs[2] = {hA, hB};
    float* cbufs[2] = {cA, cB};
    int child = 0;  // leaves in A
    for (int lvl = 8; lvl >= 0; --lvl) {
        int W = 1 << lvl, s = W - 1;
        int outb = child ^ 1;
        size_t rows = (size_t)W * 128;
        bool split = (W <= 16) &&
                     ((part_off + 3 * rows * 1024) * sizeof(float) <= ws_size);
        if (lvl >= 5 && mfma_ok) {
            mfma_level<<<dim3(W, 8), 256, 0, stream>>>(
                x_embed, hbufs[child], cbufs[child], Wth, Wtm, Wtl, bias_big,
                hbufs[outb], cbufs[outb], s);
        } else if (split) {
            gemm_part4<<<dim3(W * 2, 4, 3), 256, 0, stream>>>(
                x_embed, hbufs[child], Wbig, part, s, (int)rows);
            combine_eps<<<(int)(rows / 4), 256, 0, stream>>>(
                part, cbufs[child], bias_big, hbufs[outb], cbufs[outb], (int)rows);
        } else {
            level_kernel<<<dim3(W * 2, 4), 256, 0, stream>>>(
                x_embed, hbufs[child], cbufs[child], Wbig, bias_big,
                hbufs[outb], cbufs[outb], s);
        }
        child = outb;
    }

    final_kernel<<<128, 256, 0, stream>>>(init_emb, cbufs[child], hbufs[child],
                                          Woend, boend, out);
}